// Round 3
// baseline (75.020 us; speedup 1.0000x reference)
//
#include <hip/hip_runtime.h>
#include <stdint.h>
#include <limits.h>

// T=2,000,000 tokens, VOCAB=4, D=128, N_READS=2000, segment_ids SORTED.
//
// out[s][d] = (sum_v cnt[s][v] * E[v][d]) / max(sum_v cnt[s][v], 1)
//
// One kernel, one block per segment:
//   1. guess-centered bracketed lower_bound (boundary of segment s is at
//      s*T/R +- ~700 w.h.p.; bracket +-4096 validated with 2 broadcast
//      loads, unconditional fallback to full range) -> ~3 dependent
//      memory rounds, all probes in a ~32KB region shared with neighbors
//   2. stream tokens[lo..hi) coalesced, histogram packed in u64 (4 x u16)
//   3. shuffle + LDS reduce, emit weighted mean for 128 dims
// XCD swizzle keeps adjacent segments (overlapping probe/token regions)
// on the same XCD's L2. No workspace, no memset, no atomics, 1 graph node.

#define DIM 128
#define TPB 256
#define BRACKET 4096

// Wave-cooperative lower_bound of t in sorted a, answer known to lie in
// [lo, hi]. Caller guarantees: (lo==0 || a[lo] < t) && (hi==n || a[hi] >= t).
__device__ __forceinline__ int wave_lb(const int* __restrict__ a, int lo,
                                       int hi, int t) {
  const int lane = threadIdx.x & 63;
  while (hi - lo > 256) {
    const long long span = hi - lo;
    const int idx = lo + (int)((span * (lane + 1)) >> 6);  // lane63 -> hi
    const int probe = (idx < hi) ? a[idx] : INT_MAX;       // a[hi] = +inf
    const unsigned long long mask = __ballot(probe >= t);
    const int first = __ffsll(mask) - 1;  // mask != 0 (lane63 true)
    const int nlo = (first == 0) ? lo : lo + (int)((span * (long long)first) >> 6);
    const int nhi = lo + (int)((span * (long long)(first + 1)) >> 6);
    lo = nlo;
    hi = nhi;
  }
  // Final contiguous scan: span <= 256 = 64 lanes x 4. Sorted array =>
  // min matching index == first matching index. No match in [lo,hi) => hi.
  int pos = hi;
#pragma unroll
  for (int j = 0; j < 4; ++j) {
    const int idx = lo + lane * 4 + j;
    if (idx < hi && a[idx] >= t && idx < pos) pos = idx;
  }
#pragma unroll
  for (int off = 1; off < 64; off <<= 1) {
    pos = min(pos, __shfl_xor(pos, off, 64));
  }
  return pos;
}

__global__ __launch_bounds__(TPB) void seg_mean_kernel(
    const int* __restrict__ tokens, const int* __restrict__ segs,
    const float* __restrict__ emb, float* __restrict__ out, int T,
    int n_reads) {
  // XCD-aware swizzle: consecutive blockIdx round-robin across 8 XCDs;
  // give each XCD a contiguous range of segments for L2 locality.
  int s = blockIdx.x;
  if ((gridDim.x & 7) == 0) {
    const int per = gridDim.x >> 3;
    s = (int)(blockIdx.x & 7) * per + (int)(blockIdx.x >> 3);
  }

  const int tid = threadIdx.x;
  const int wave = tid >> 6;

  __shared__ int bounds[2];
  __shared__ unsigned long long red[TPB / 64];

  if (wave < 2) {
    const int t = s + wave;  // wave0: lower bound of s; wave1: of s+1
    // Statistical guess with validated bracket (falls back to full range).
    const int g = (int)(((long long)t * T) / n_reads);
    int blo = g - BRACKET;
    if (blo < 0) blo = 0;
    int bhi = g + BRACKET;
    if (bhi > T) bhi = T;
    const bool okl = (blo == 0) || (segs[blo] < t);    // broadcast load
    const bool okr = (bhi == T) || (segs[bhi] >= t);   // broadcast load
    if (!(okl && okr)) {
      blo = 0;
      bhi = T;
    }
    const int r = wave_lb(segs, blo, bhi, t);
    if ((tid & 63) == 0) bounds[wave] = r;
  }
  __syncthreads();
  const int lo = bounds[0];
  const int hi = bounds[1];

  // Packed histogram: u64 as 4 x u16 lanes (segment size << 65536).
  unsigned long long acc = 0ULL;
  for (int i = lo + tid; i < hi; i += TPB) {
    acc += 1ULL << ((tokens[i] & 3) << 4);
  }

#pragma unroll
  for (int off = 32; off > 0; off >>= 1) {
    acc += __shfl_down(acc, off, 64);
  }
  if ((tid & 63) == 0) red[wave] = acc;
  __syncthreads();
  if (tid == 0) {
    red[0] = red[0] + red[1] + red[2] + red[3];
  }
  __syncthreads();

  const unsigned long long c = red[0];
  if (tid < DIM) {
    const float c0 = (float)(unsigned)(c & 0xFFFFULL);
    const float c1 = (float)(unsigned)((c >> 16) & 0xFFFFULL);
    const float c2 = (float)(unsigned)((c >> 32) & 0xFFFFULL);
    const float c3 = (float)(unsigned)((c >> 48) & 0xFFFFULL);
    const float tot = fmaxf(c0 + c1 + c2 + c3, 1.0f);  // ref: max(counts, 1)
    const float v = c0 * emb[tid] + c1 * emb[DIM + tid] +
                    c2 * emb[2 * DIM + tid] + c3 * emb[3 * DIM + tid];
    out[(long long)s * DIM + tid] = v / tot;
  }
}

extern "C" void kernel_launch(void* const* d_in, const int* in_sizes, int n_in,
                              void* d_out, int out_size, void* d_ws,
                              size_t ws_size, hipStream_t stream) {
  const int* tokens = (const int*)d_in[0];
  const int* segs = (const int*)d_in[1];
  const float* emb = (const float*)d_in[2];
  float* out = (float*)d_out;

  const int T = in_sizes[0];
  const int n_reads = out_size / DIM;  // 2000

  seg_mean_kernel<<<n_reads, TPB, 0, stream>>>(tokens, segs, emb, out, T,
                                               n_reads);
}

// Round 4
// 71.253 us; speedup vs baseline: 1.0529x; 1.0529x over previous
//
#include <hip/hip_runtime.h>
#include <stdint.h>

// T=2,000,000 tokens, VOCAB=4, D=128, N_READS=2000, segment_ids SORTED.
//
// out[s][d] = (sum_v cnt[s][v] * E[v][d]) / max(sum_v cnt[s][v], 1)
//
// One kernel, one block per segment (R2 configuration — best measured):
//   1. wave-parallel 64-ary lower_bound on sorted segs for [s, s+1) bounds
//      (waves 0 and 1 search in parallel; ~4 probe rounds each)
//   2. stream tokens[lo..hi) coalesced, histogram packed in u64 (4 x u16)
//   3. shuffle + LDS reduce, emit weighted mean for 128 dims
// No workspace, no memset, no global atomics, single graph node.
//
// NOTE (R3 post-mortem): bracketed/guessed search + XCD swizzle measured
// +3.5us vs this version — within harness reset-floor noise (~68-72us of
// 256MB d_ws poison fills at ~80% HBM peak dominate dur_us). Reverted.

#define DIM 128
#define TPB 256

__device__ __forceinline__ int wave_lower_bound(const int* __restrict__ a,
                                                int n, int t) {
  const int lane = threadIdx.x & 63;
  int lo = 0, hi = n;  // answer (first idx with a[idx] >= t) is in [lo, hi]
  while (hi - lo > 64) {
    const long long span = hi - lo;
    const int idx = lo + (int)((span * (lane + 1)) >> 6);  // lane63 -> hi
    const int probe = (idx < hi) ? a[idx] : 0x7fffffff;    // a[hi] = +inf
    const unsigned long long mask = __ballot(probe >= t);
    const int first = __ffsll(mask) - 1;  // mask != 0 (lane63 true)
    const int nlo = (first == 0) ? lo : lo + (int)((span * (long long)first) >> 6);
    const int nhi = lo + (int)((span * (long long)(first + 1)) >> 6);
    lo = nlo;
    hi = nhi;
  }
  const int idx = lo + lane;
  const bool ge = (idx < hi) ? (a[idx] >= t) : true;
  const unsigned long long mask = __ballot(ge);
  return lo + __ffsll(mask) - 1;
}

__global__ __launch_bounds__(TPB) void seg_mean_kernel(
    const int* __restrict__ tokens, const int* __restrict__ segs,
    const float* __restrict__ emb, float* __restrict__ out, int T) {
  const int s = blockIdx.x;
  const int tid = threadIdx.x;
  const int wave = tid >> 6;

  __shared__ int bounds[2];
  __shared__ unsigned long long red[TPB / 64];

  if (wave < 2) {
    const int r = wave_lower_bound(segs, T, s + wave);
    if ((tid & 63) == 0) bounds[wave] = r;
  }
  __syncthreads();
  const int lo = bounds[0];
  const int hi = bounds[1];

  // Packed histogram: u64 as 4 x u16 lanes (per-thread <= ~5 per lane,
  // per-wave <= ~320, per-block <= ~1300 -- no u16 overflow).
  unsigned long long acc = 0ULL;
  for (int i = lo + tid; i < hi; i += TPB) {
    acc += 1ULL << ((tokens[i] & 3) << 4);
  }

#pragma unroll
  for (int off = 32; off > 0; off >>= 1) {
    acc += __shfl_down(acc, off, 64);
  }
  if ((tid & 63) == 0) red[wave] = acc;
  __syncthreads();
  if (tid == 0) {
    red[0] = red[0] + red[1] + red[2] + red[3];
  }
  __syncthreads();

  const unsigned long long c = red[0];
  if (tid < DIM) {
    const float c0 = (float)(unsigned)(c & 0xFFFFULL);
    const float c1 = (float)(unsigned)((c >> 16) & 0xFFFFULL);
    const float c2 = (float)(unsigned)((c >> 32) & 0xFFFFULL);
    const float c3 = (float)(unsigned)((c >> 48) & 0xFFFFULL);
    const float tot = fmaxf(c0 + c1 + c2 + c3, 1.0f);  // ref: max(counts, 1)
    const float v = c0 * emb[tid] + c1 * emb[DIM + tid] +
                    c2 * emb[2 * DIM + tid] + c3 * emb[3 * DIM + tid];
    out[(long long)s * DIM + tid] = v / tot;
  }
}

extern "C" void kernel_launch(void* const* d_in, const int* in_sizes, int n_in,
                              void* d_out, int out_size, void* d_ws,
                              size_t ws_size, hipStream_t stream) {
  const int* tokens = (const int*)d_in[0];
  const int* segs = (const int*)d_in[1];
  const float* emb = (const float*)d_in[2];
  float* out = (float*)d_out;

  const int T = in_sizes[0];
  const int n_reads = out_size / DIM;  // 2000

  seg_mean_kernel<<<n_reads, TPB, 0, stream>>>(tokens, segs, emb, out, T);
}